// Round 1
// baseline (681.675 us; speedup 1.0000x reference)
//
#include <hip/hip_runtime.h>
#include <stdint.h>

// ---------------------------------------------------------------------------
// InvariantPointAttention, B=1 N=768 CS=384 CZ=128 CH=16 H=12 PQ=4 PV=8
//
// KEY STRUCTURAL SIMPLIFICATION (exact math, input-independent):
//   weight = softmax over a size-1 axis == 1.0  =>  _mix(x) == x[:,:,0].
//   Only frame 0 of se / rotations is ever used.
//
// Pipeline:
//   K1 k_se   : se0 = LN(s @ wexp[0:384].T + bexp[0:384]) * g + b
//   K2 k_proj : q,k,v,q_pts,k_pts,v_pts (+ K2 = sum k_pts^2); k/v/pts -> bf16
//   K3 k_attn : flash-style per query row; online softmax over j;
//               bias & o_pair via mfma_f32_16x16x32_bf16; z read ONCE (302MB)
//   K4 k_gemm : out_part = cat @ wout.T  (fp32, split-K=12)
//   K5 k_red  : out = sum parts + bout
// ---------------------------------------------------------------------------

typedef float f32x4 __attribute__((ext_vector_type(4)));
typedef short s16x8 __attribute__((ext_vector_type(8)));

__device__ __forceinline__ float bf2f(unsigned short u) {
    union { unsigned int i; float f; } v; v.i = ((unsigned int)u) << 16; return v.f;
}
__device__ __forceinline__ float bf2fs(short s) { return bf2f((unsigned short)s); }
__device__ __forceinline__ unsigned short f2bf(float f) {
    union { float f; unsigned int i; } v; v.f = f;
    unsigned int r = v.i + 0x7fffu + ((v.i >> 16) & 1u);
    return (unsigned short)(r >> 16);
}

// ------------------------------- K1: se0 -----------------------------------
__global__ __launch_bounds__(256) void k_se(
    const float* __restrict__ s, const float* __restrict__ wexp,
    const float* __restrict__ bexp, const float* __restrict__ ln_g,
    const float* __restrict__ ln_b, float* __restrict__ se0)
{
    const int n0 = blockIdx.x * 4;
    const int t  = threadIdx.x;
    __shared__ float se_l[4 * 384];
    __shared__ float mu_s[4], rs_s[4];

    const bool has1 = (t < 128);
    const float* wr0 = wexp + (size_t)t * 384;
    const float* wr1 = wexp + (size_t)(t + 256) * 384;
    float a0[4] = {0.f,0.f,0.f,0.f}, a1[4] = {0.f,0.f,0.f,0.f};

    for (int k4 = 0; k4 < 96; ++k4) {
        f32x4 sv[4];
        #pragma unroll
        for (int r = 0; r < 4; ++r)
            sv[r] = *(const f32x4*)(s + (size_t)(n0 + r) * 384 + k4 * 4); // uniform -> s_load
        f32x4 w0 = *(const f32x4*)(wr0 + k4 * 4);
        #pragma unroll
        for (int m = 0; m < 4; ++m) {
            float wv = w0[m];
            #pragma unroll
            for (int r = 0; r < 4; ++r) a0[r] += sv[r][m] * wv;
        }
        if (has1) {
            f32x4 w1 = *(const f32x4*)(wr1 + k4 * 4);
            #pragma unroll
            for (int m = 0; m < 4; ++m) {
                float wv = w1[m];
                #pragma unroll
                for (int r = 0; r < 4; ++r) a1[r] += sv[r][m] * wv;
            }
        }
    }
    {
        float b0 = bexp[t];
        #pragma unroll
        for (int r = 0; r < 4; ++r) se_l[r * 384 + t] = a0[r] + b0;
        if (has1) {
            float b1 = bexp[t + 256];
            #pragma unroll
            for (int r = 0; r < 4; ++r) se_l[r * 384 + t + 256] = a1[r] + b1;
        }
    }
    __syncthreads();
    // LayerNorm: wave w handles row w
    {
        const int w = t >> 6, lane = t & 63;
        float s1 = 0.f, s2 = 0.f;
        #pragma unroll
        for (int q = 0; q < 6; ++q) {
            float v = se_l[w * 384 + lane + q * 64];
            s1 += v; s2 += v * v;
        }
        for (int mk = 1; mk < 64; mk <<= 1) {
            s1 += __shfl_xor(s1, mk, 64);
            s2 += __shfl_xor(s2, mk, 64);
        }
        if (lane == 0) {
            float mu = s1 * (1.f / 384.f);
            float var = s2 * (1.f / 384.f) - mu * mu;
            mu_s[w] = mu;
            rs_s[w] = rsqrtf(fmaxf(var, 0.f) + 1e-5f);
        }
    }
    __syncthreads();
    for (int x = t; x < 4 * 384; x += 256) {
        int r = x / 384, c = x - r * 384;
        se0[(size_t)(n0 + r) * 384 + c] = (se_l[x] - mu_s[r]) * rs_s[r] * ln_g[c] + ln_b[c];
    }
}

// ------------------------------- K2: projections ---------------------------
__device__ __forceinline__ void wmap(int c,
    const float* wq, const float* bq, const float* wkv, const float* bkv,
    const float* wqp, const float* bqp, const float* wkvp, const float* bkvp,
    const float** w, float* b)
{
    if (c < 192)      { *w = wq   + (size_t)c * 384;         *b = bq[c]; }
    else if (c < 576) { *w = wkv  + (size_t)(c - 192) * 384; *b = bkv[c - 192]; }
    else if (c < 720) { *w = wqp  + (size_t)(c - 576) * 384; *b = bqp[c - 576]; }
    else              { *w = wkvp + (size_t)(c - 720) * 384; *b = bkvp[c - 720]; }
}

__global__ __launch_bounds__(256) void k_proj(
    const float* __restrict__ se0,
    const float* __restrict__ wq,  const float* __restrict__ bq,
    const float* __restrict__ wkv, const float* __restrict__ bkv,
    const float* __restrict__ wqp, const float* __restrict__ bqp,
    const float* __restrict__ wkvp,const float* __restrict__ bkvp,
    const float* __restrict__ r_rot, const float* __restrict__ r_trans,
    float* __restrict__ q_out, unsigned short* __restrict__ k_out,
    unsigned short* __restrict__ v_out, float* __restrict__ qp_out,
    unsigned short* __restrict__ kp_out, unsigned short* __restrict__ vp_out,
    float* __restrict__ k2_out)
{
    const int n0 = blockIdx.x * 8;
    const int cb = blockIdx.y;          // 0: q/kv cols [0,576), 1: pts cols [576,1152)
    const int t  = threadIdx.x;
    const int cbase = cb * 576;
    __shared__ float lin[8 * 576];
    __shared__ float kprot[8 * 144];

    const bool has2 = (t < 64);
    const float *w0p, *w1p, *w2p; float b0, b1, b2;
    wmap(cbase + t,        wq, bq, wkv, bkv, wqp, bqp, wkvp, bkvp, &w0p, &b0);
    wmap(cbase + t + 256,  wq, bq, wkv, bkv, wqp, bqp, wkvp, bkvp, &w1p, &b1);
    if (has2) wmap(cbase + t + 512, wq, bq, wkv, bkv, wqp, bqp, wkvp, bkvp, &w2p, &b2);
    else { w2p = wq; b2 = 0.f; }

    float ac0[8] = {}, ac1[8] = {}, ac2[8] = {};
    for (int k4 = 0; k4 < 96; ++k4) {
        f32x4 sv[8];
        #pragma unroll
        for (int r = 0; r < 8; ++r)
            sv[r] = *(const f32x4*)(se0 + (size_t)(n0 + r) * 384 + k4 * 4); // uniform
        f32x4 wv0 = *(const f32x4*)(w0p + k4 * 4);
        f32x4 wv1 = *(const f32x4*)(w1p + k4 * 4);
        #pragma unroll
        for (int m = 0; m < 4; ++m) {
            float a = wv0[m], b = wv1[m];
            #pragma unroll
            for (int r = 0; r < 8; ++r) { ac0[r] += sv[r][m] * a; ac1[r] += sv[r][m] * b; }
        }
        if (has2) {
            f32x4 wv2 = *(const f32x4*)(w2p + k4 * 4);
            #pragma unroll
            for (int m = 0; m < 4; ++m) {
                float a = wv2[m];
                #pragma unroll
                for (int r = 0; r < 8; ++r) ac2[r] += sv[r][m] * a;
            }
        }
    }
    #pragma unroll
    for (int r = 0; r < 8; ++r) {
        lin[r * 576 + t]       = ac0[r] + b0;
        lin[r * 576 + t + 256] = ac1[r] + b1;
    }
    if (has2) {
        #pragma unroll
        for (int r = 0; r < 8; ++r) lin[r * 576 + t + 512] = ac2[r] + b2;
    }
    __syncthreads();

    if (cb == 0) {
        for (int x = t; x < 8 * 576; x += 256) {
            int r = x / 576, lc = x - r * 576;
            int n = n0 + r;
            float v = lin[x];
            if (lc < 192) q_out[(size_t)n * 192 + lc] = v;
            else {
                int l2 = lc - 192, h = l2 >> 5, c = l2 & 31;
                if (c < 16) k_out[(size_t)n * 192 + h * 16 + c] = f2bf(v);
                else        v_out[(size_t)n * 192 + h * 16 + (c - 16)] = f2bf(v);
            }
        }
    } else {
        for (int x = t; x < 8 * 576; x += 256) {
            int r = x / 576, y = x - r * 576;
            int pt = y / 3, i = y - pt * 3;
            int n = n0 + r;
            const float* rot = r_rot + (size_t)n * 45;        // frame 0
            float t0 = r_trans[(size_t)n * 15 + i];
            float v;
            if (pt < 48) {   // q_pts: local cols j*48+pt
                v = rot[i*3+0] * lin[r*576 + pt]
                  + rot[i*3+1] * lin[r*576 + 48 + pt]
                  + rot[i*3+2] * lin[r*576 + 96 + pt] + t0;
                qp_out[(size_t)n * 144 + pt * 3 + i] = v;
            } else {         // kv_pts: local cols 144 + j*144 + pp
                int pp = pt - 48;
                v = rot[i*3+0] * lin[r*576 + 144 + pp]
                  + rot[i*3+1] * lin[r*576 + 288 + pp]
                  + rot[i*3+2] * lin[r*576 + 432 + pp] + t0;
                int h = pp / 12, pl = pp - h * 12;
                if (pl < 4) {
                    kp_out[(size_t)n * 144 + (h * 4 + pl) * 3 + i] = f2bf(v);
                    kprot[r * 144 + (h * 4 + pl) * 3 + i] = v;
                } else {
                    vp_out[(size_t)n * 288 + (h * 8 + (pl - 4)) * 3 + i] = f2bf(v);
                }
            }
        }
        __syncthreads();
        if (t < 96) {
            int r = t / 12, h = t - r * 12;
            float ss = 0.f;
            #pragma unroll
            for (int d = 0; d < 12; ++d) {
                float v = kprot[r * 144 + h * 12 + d];
                ss += v * v;
            }
            k2_out[(size_t)(n0 + r) * 12 + h] = ss;
        }
    }
}

// ------------------------------- K3: fused attention -----------------------
__global__ __launch_bounds__(256) void k_attn(
    const float* __restrict__ z, const float* __restrict__ mask,
    const float* __restrict__ head_w, const float* __restrict__ wb,
    const float* __restrict__ bb,
    const float* __restrict__ r_rot, const float* __restrict__ r_trans,
    const float* __restrict__ q_ws, const float* __restrict__ qp_ws,
    const float* __restrict__ k2_ws,
    const unsigned short* __restrict__ k_bf, const unsigned short* __restrict__ v_bf,
    const unsigned short* __restrict__ kp_bf, const unsigned short* __restrict__ vp_bf,
    float* __restrict__ cat)
{
    const int i = blockIdx.x;
    const int t = threadIdx.x;
    const int lane = t & 63, wv = t >> 6;
    const int quad = lane >> 4, lcol = lane & 15;

    __shared__ short zb[64 * 136];     // z tile, bf16, row stride 136
    __shared__ short kt[64 * 200];     // k tile, bf16
    __shared__ short kpt[64 * 146];    // k_pts tile, bf16
    __shared__ float L[64 * 17];       // logits [jl][h]
    __shared__ float Pt[16 * 68];      // softmax weights [h][jl]
    __shared__ float qs[192], qps[144];
    __shared__ float K2t[64 * 13], ulrt[64];
    __shared__ float m_s[16], l_s[16], alph_s[16], linv_s[16];
    __shared__ float cpt[16], cbbb[16], q2s[16];
    __shared__ float optb[288];

    const float c_qk = 0.14433756729740643f;  // 1/sqrt(3*CH)
    const float c_b  = 0.57735026918962576f;  // 1/sqrt(3)

    if (t < 192) qs[t]  = q_ws[(size_t)i * 192 + t];
    if (t < 144) qps[t] = qp_ws[(size_t)i * 144 + t];
    if (t < 16) { m_s[t] = -1e30f; l_s[t] = 0.f; alph_s[t] = 1.f; }
    if (t < 16) {
        if (t < 12) {
            float x = head_w[t];
            float sp = logf(1.f + __expf(x));                 // softplus
            cpt[t]  = -0.5f * sp * 0.13608276348795434f;      // * 1/sqrt(54)
            cbbb[t] = c_b * bb[t];
        } else { cpt[t] = 0.f; cbbb[t] = 0.f; }
    }
    for (int x = t; x < 4 * 68; x += 256) Pt[12 * 68 + x] = 0.f;  // pad heads = 0
    const float ulr_i = mask[(size_t)i * 5];

    // wb B-fragments (B[k=c][n=h]), resident in registers for the whole kernel
    s16x8 wbf[4];
    #pragma unroll
    for (int kb = 0; kb < 4; ++kb) {
        #pragma unroll
        for (int j = 0; j < 8; ++j) {
            int c = kb * 32 + quad * 8 + j;
            wbf[kb][j] = (lcol < 12) ? (short)f2bf(wb[(size_t)lcol * 128 + c]) : (short)0;
        }
    }
    __syncthreads();
    if (t < 16) {
        if (t < 12) {
            float ss = 0.f;
            #pragma unroll
            for (int d = 0; d < 12; ++d) { float v = qps[t * 12 + d]; ss += v * v; }
            q2s[t] = ss;
        } else q2s[t] = 0.f;
    }

    f32x4 acc_op[2] = { {0.f,0.f,0.f,0.f}, {0.f,0.f,0.f,0.f} };  // o_pair (MFMA C)
    f32x4 acc_s = {0.f,0.f,0.f,0.f};                              // o / o_pt scalar
    int role_h = -1;
    if (t < 48) role_h = t >> 2;
    else if (t >= 64 && t < 136) role_h = ((t - 64) * 4) / 24;

    for (int jt = 0; jt < 12; ++jt) {
        const int j0 = jt * 64;
        __syncthreads();   // protect LDS vs previous tile readers

        // ---- stage tiles ----
        {
            const float* zrow = z + (size_t)i * 98304 + (size_t)j0 * 128;
            #pragma unroll
            for (int s = 0; s < 8; ++s) {
                int idx = t + s * 256;
                f32x4 v = *(const f32x4*)(zrow + idx * 4);
                int jl = idx >> 5, c4 = (idx & 31) * 4;
                uint2 pk;
                pk.x = (unsigned)f2bf(v[0]) | ((unsigned)f2bf(v[1]) << 16);
                pk.y = (unsigned)f2bf(v[2]) | ((unsigned)f2bf(v[3]) << 16);
                *(uint2*)&zb[jl * 136 + c4] = pk;
            }
            const uint4* ksrc = (const uint4*)(k_bf + (size_t)j0 * 192);
            #pragma unroll
            for (int s = 0; s < 6; ++s) {
                int idx = t + s * 256;
                uint4 vk = ksrc[idx];
                int jl = idx / 24, c = (idx - jl * 24) * 8;
                *(uint4*)&kt[jl * 200 + c] = vk;
            }
            const uint2* kpsrc = (const uint2*)(kp_bf + (size_t)j0 * 144);
            #pragma unroll
            for (int s = 0; s < 9; ++s) {
                int idx = t + s * 256;
                uint2 vk = kpsrc[idx];
                int jl = idx / 36, c = (idx - jl * 36) * 4;
                *(unsigned int*)&kpt[jl * 146 + c]     = vk.x;
                *(unsigned int*)&kpt[jl * 146 + c + 2] = vk.y;
            }
            #pragma unroll
            for (int s = 0; s < 3; ++s) {
                int x = t + s * 256;
                int jl = x / 12, h = x - jl * 12;
                K2t[jl * 13 + h] = k2_ws[(size_t)j0 * 12 + x];
            }
            if (t < 64) ulrt[t] = mask[(size_t)(j0 + t) * 5];
        }
        __syncthreads();

        // ---- bias via MFMA: D[jl16][h] = z_tile(16x128) @ wb^T(128x16) ----
        {
            f32x4 d = {0.f,0.f,0.f,0.f};
            #pragma unroll
            for (int kb = 0; kb < 4; ++kb) {
                s16x8 a = *(const s16x8*)&zb[(wv * 16 + lcol) * 136 + kb * 32 + quad * 8];
                d = __builtin_amdgcn_mfma_f32_16x16x32_bf16(a, wbf[kb], d, 0, 0, 0);
            }
            if (lcol < 12) {
                #pragma unroll
                for (int r = 0; r < 4; ++r)
                    L[(wv * 16 + quad * 4 + r) * 17 + lcol] = c_b * d[r] + cbbb[lcol];
            }
        }
        __syncthreads();

        // ---- scalar qk + point-distance + mask terms ----
        #pragma unroll
        for (int es = 0; es < 3; ++es) {
            int e = t + es * 256;
            int h = e >> 6, jl = e & 63;
            f32x4 qv0 = *(const f32x4*)&qs[h * 16];
            f32x4 qv1 = *(const f32x4*)&qs[h * 16 + 4];
            f32x4 qv2 = *(const f32x4*)&qs[h * 16 + 8];
            f32x4 qv3 = *(const f32x4*)&qs[h * 16 + 12];
            s16x8 k0 = *(const s16x8*)&kt[jl * 200 + h * 16];
            s16x8 k1 = *(const s16x8*)&kt[jl * 200 + h * 16 + 8];
            float qk = 0.f;
            #pragma unroll
            for (int m = 0; m < 4; ++m) {
                qk += qv0[m] * bf2fs(k0[m]);
                qk += qv1[m] * bf2fs(k0[4 + m]);
                qk += qv2[m] * bf2fs(k1[m]);
                qk += qv3[m] * bf2fs(k1[4 + m]);
            }
            float dp = 0.f;
            #pragma unroll
            for (int dd = 0; dd < 6; ++dd) {
                unsigned int u = *(const unsigned int*)&kpt[jl * 146 + h * 12 + dd * 2];
                dp += qps[h * 12 + dd * 2]     * bf2f((unsigned short)(u & 0xffffu));
                dp += qps[h * 12 + dd * 2 + 1] * bf2f((unsigned short)(u >> 16));
            }
            float ptt = cpt[h] * (q2s[h] + K2t[jl * 13 + h] - 2.f * dp);
            float lg = c_qk * qk + ptt + 1e5f * (ulr_i * ulrt[jl] - 1.f);
            L[jl * 17 + h] += lg;
        }
        __syncthreads();

        // ---- online softmax update (16 lanes per head) ----
        if (t < 192) {
            int h = t >> 4, u = t & 15;
            float v0 = L[(u * 4 + 0) * 17 + h];
            float v1 = L[(u * 4 + 1) * 17 + h];
            float v2 = L[(u * 4 + 2) * 17 + h];
            float v3 = L[(u * 4 + 3) * 17 + h];
            float mx = fmaxf(fmaxf(v0, v1), fmaxf(v2, v3));
            for (int mk = 1; mk < 16; mk <<= 1) mx = fmaxf(mx, __shfl_xor(mx, mk, 16));
            float mold = m_s[h];
            float mnew = fmaxf(mold, mx);
            float w0 = __expf(v0 - mnew), w1 = __expf(v1 - mnew);
            float w2 = __expf(v2 - mnew), w3 = __expf(v3 - mnew);
            Pt[h * 68 + u * 4 + 0] = w0;
            Pt[h * 68 + u * 4 + 1] = w1;
            Pt[h * 68 + u * 4 + 2] = w2;
            Pt[h * 68 + u * 4 + 3] = w3;
            float sm = w0 + w1 + w2 + w3;
            for (int mk = 1; mk < 16; mk <<= 1) sm += __shfl_xor(sm, mk, 16);
            if (u == 0) {
                float al = __expf(mold - mnew);
                m_s[h] = mnew; alph_s[h] = al;
                l_s[h] = l_s[h] * al + sm;
            }
        }
        __syncthreads();

        // ---- accumulate: o_pair via MFMA  D[h][c] += P(16x64) @ z(64x128) ----
        {
            float al[4];
            #pragma unroll
            for (int r = 0; r < 4; ++r) al[r] = alph_s[quad * 4 + r];
            #pragma unroll
            for (int nt = 0; nt < 2; ++nt)
                #pragma unroll
                for (int r = 0; r < 4; ++r) acc_op[nt][r] *= al[r];
            #pragma unroll
            for (int kb = 0; kb < 2; ++kb) {
                f32x4 pa = *(const f32x4*)&Pt[lcol * 68 + kb * 32 + quad * 8];
                f32x4 pb = *(const f32x4*)&Pt[lcol * 68 + kb * 32 + quad * 8 + 4];
                s16x8 af;
                af[0] = (short)f2bf(pa[0]); af[1] = (short)f2bf(pa[1]);
                af[2] = (short)f2bf(pa[2]); af[3] = (short)f2bf(pa[3]);
                af[4] = (short)f2bf(pb[0]); af[5] = (short)f2bf(pb[1]);
                af[6] = (short)f2bf(pb[2]); af[7] = (short)f2bf(pb[3]);
                #pragma unroll
                for (int nt = 0; nt < 2; ++nt) {
                    int c = wv * 32 + nt * 16 + lcol;
                    s16x8 bfg;
                    #pragma unroll
                    for (int j = 0; j < 8; ++j)
                        bfg[j] = zb[(kb * 32 + quad * 8 + j) * 136 + c];
                    acc_op[nt] = __builtin_amdgcn_mfma_f32_16x16x32_bf16(af, bfg, acc_op[nt], 0, 0, 0);
                }
            }
        }
        // ---- scalar o (t<48) and o_pt (64<=t<136), bf16 v / v_pts from L2 ----
        if (role_h >= 0) {
            float alpha = alph_s[role_h];
            f32x4 a = acc_s;
            a[0] *= alpha; a[1] *= alpha; a[2] *= alpha; a[3] *= alpha;
            const unsigned int* src;
            int stride_u, off_u;
            if (t < 48) { src = (const unsigned int*)v_bf;  stride_u = 96;  off_u = t * 2; }
            else        { src = (const unsigned int*)vp_bf; stride_u = 144; off_u = (t - 64) * 2; }
            const float* prow = &Pt[role_h * 68];
            #pragma unroll 4
            for (int jl = 0; jl < 64; jl += 4) {
                f32x4 p = *(const f32x4*)(prow + jl);
                #pragma unroll
                for (int m = 0; m < 4; ++m) {
                    uint2 w = *(const uint2*)(src + (size_t)(j0 + jl + m) * stride_u + off_u);
                    float pm = p[m];
                    a[0] += pm * bf2f((unsigned short)(w.x & 0xffffu));
                    a[1] += pm * bf2f((unsigned short)(w.x >> 16));
                    a[2] += pm * bf2f((unsigned short)(w.y & 0xffffu));
                    a[3] += pm * bf2f((unsigned short)(w.y >> 16));
                }
            }
            acc_s = a;
        }
    }

    // ------------------------------ epilogue -------------------------------
    __syncthreads();
    if (t < 16) linv_s[t] = (t < 12) ? 1.f / l_s[t] : 0.f;
    __syncthreads();
    float* crow = cat + (size_t)i * 2112;
    if (t < 48) {
        float li = linv_s[role_h];
        f32x4 o = acc_s;
        o[0] *= li; o[1] *= li; o[2] *= li; o[3] *= li;
        *(f32x4*)(crow + t * 4) = o;
    }
    if (t >= 64 && t < 136) {
        float li = linv_s[role_h];
        int e0 = (t - 64) * 4;
        optb[e0 + 0] = acc_s[0] * li;
        optb[e0 + 1] = acc_s[1] * li;
        optb[e0 + 2] = acc_s[2] * li;
        optb[e0 + 3] = acc_s[3] * li;
    }
    {
        #pragma unroll
        for (int nt = 0; nt < 2; ++nt)
            #pragma unroll
            for (int r = 0; r < 4; ++r) {
                int h = quad * 4 + r;
                if (h < 12)
                    crow[576 + h * 128 + wv * 32 + nt * 16 + lcol] = acc_op[nt][r] * linv_s[h];
            }
    }
    __syncthreads();
    if (t < 96) {   // invert frame 0, write o_pt xyz + norm
        int hp = t;
        const float* rot = r_rot + (size_t)i * 45;
        float d0 = optb[hp * 3 + 0] - r_trans[(size_t)i * 15 + 0];
        float d1 = optb[hp * 3 + 1] - r_trans[(size_t)i * 15 + 1];
        float d2 = optb[hp * 3 + 2] - r_trans[(size_t)i * 15 + 2];
        float f0 = rot[0] * d0 + rot[3] * d1 + rot[6] * d2;
        float f1 = rot[1] * d0 + rot[4] * d1 + rot[7] * d2;
        float f2 = rot[2] * d0 + rot[5] * d1 + rot[8] * d2;
        crow[192 + hp] = f0;
        crow[288 + hp] = f1;
        crow[384 + hp] = f2;
        crow[480 + hp] = sqrtf(f0 * f0 + f1 * f1 + f2 * f2 + 1e-8f);
    }
}

// ------------------------------- K4: out = cat @ wout.T (split-K) ----------
__global__ __launch_bounds__(256) void k_gemm(
    const float* __restrict__ cat, const float* __restrict__ wout,
    float* __restrict__ part)
{
    const int mb = blockIdx.x, nb = blockIdx.y, sb = blockIdx.z;
    const int t = threadIdx.x;
    __shared__ float At[16 * 132];
    __shared__ float Bt[16 * 68];
    const int m0 = mb * 128, n0 = nb * 64, koff = sb * 176;
    const int tx = t & 15, ty = t >> 4;
    float acc[8][4] = {};

    for (int ch = 0; ch < 11; ++ch) {
        const int kb = koff + ch * 16;
        __syncthreads();
        #pragma unroll
        for (int s = 0; s < 2; ++s) {
            int idx = t + s * 256;
            int row = idx >> 2, k4 = idx & 3;
            f32x4 v = *(const f32x4*)(cat + (size_t)(m0 + row) * 2112 + kb + k4 * 4);
            At[(k4 * 4 + 0) * 132 + row] = v[0];
            At[(k4 * 4 + 1) * 132 + row] = v[1];
            At[(k4 * 4 + 2) * 132 + row] = v[2];
            At[(k4 * 4 + 3) * 132 + row] = v[3];
        }
        {
            int c = t >> 2, k4 = t & 3;
            f32x4 v = *(const f32x4*)(wout + (size_t)(n0 + c) * 2112 + kb + k4 * 4);
            Bt[(k4 * 4 + 0) * 68 + c] = v[0];
            Bt[(k4 * 4 + 1) * 68 + c] = v[1];
            Bt[(k4 * 4 + 2) * 68 + c] = v[2];
            Bt[(k4 * 4 + 3) * 68 + c] = v[3];
        }
        __syncthreads();
        #pragma unroll
        for (int kk = 0; kk < 16; ++kk) {
            f32x4 b  = *(const f32x4*)&Bt[kk * 68 + tx * 4];
            f32x4 a0 = *(const f32x4*)&At[kk * 132 + ty * 8];
            f32x4 a1 = *(const f32x4*)&At[kk * 132 + ty * 8 + 4];
            #pragma unroll
            for (int r = 0; r < 4; ++r)
                #pragma unroll
                for (int c = 0; c < 4; ++c) acc[r][c] += a0[r] * b[c];
            #pragma unroll
            for (int r = 0; r < 4; ++r)
                #pragma unroll
                for (int c = 0; c < 4; ++c) acc[r + 4][c] += a1[r] * b[c];
        }
    }
    #pragma unroll
    for (int r = 0; r < 8; ++r) {
        f32x4 v = { acc[r][0], acc[r][1], acc[r][2], acc[r][3] };
        *(f32x4*)(part + (size_t)sb * 294912 + (size_t)(m0 + ty * 8 + r) * 384 + n0 + tx * 4) = v;
    }
}

// ------------------------------- K5: reduce partials -----------------------
__global__ __launch_bounds__(256) void k_red(
    const float* __restrict__ part, const float* __restrict__ bout,
    float* __restrict__ out)
{
    const int x = blockIdx.x * 256 + threadIdx.x;   // < 294912
    float s = bout[x % 384];
    #pragma unroll
    for (int p = 0; p < 12; ++p) s += part[(size_t)p * 294912 + x];
    out[x] = s;
}

// ------------------------------- launch ------------------------------------
extern "C" void kernel_launch(void* const* d_in, const int* in_sizes, int n_in,
                              void* d_out, int out_size, void* d_ws, size_t ws_size,
                              hipStream_t stream)
{
    const float* s       = (const float*)d_in[0];
    const float* z       = (const float*)d_in[1];
    const float* r_rot   = (const float*)d_in[2];
    const float* r_trans = (const float*)d_in[3];
    const float* mask    = (const float*)d_in[4];
    const float* wq      = (const float*)d_in[5];
    const float* bq      = (const float*)d_in[6];
    const float* wkv     = (const float*)d_in[7];
    const float* bkv     = (const float*)d_in[8];
    const float* wqp     = (const float*)d_in[9];
    const float* bqp     = (const float*)d_in[10];
    const float* wkvp    = (const float*)d_in[11];
    const float* bkvp    = (const float*)d_in[12];
    const float* wb      = (const float*)d_in[13];
    const float* bb      = (const float*)d_in[14];
    const float* head_w  = (const float*)d_in[15];
    const float* wout    = (const float*)d_in[16];
    const float* bout    = (const float*)d_in[17];
    const float* wexp    = (const float*)d_in[18];
    const float* bexp    = (const float*)d_in[19];
    const float* ln_g    = (const float*)d_in[20];
    const float* ln_b    = (const float*)d_in[21];
    // d_in[22]=ww, d_in[23]=bw: unused — softmax over a size-1 axis is 1.0.

    float* wsf  = (float*)d_ws;
    float* se0  = wsf;                 // 294912
    float* qf   = wsf + 294912;        // 147456
    float* qpf  = wsf + 442368;        // 110592
    float* k2w  = wsf + 552960;        // 9216
    float* catb = wsf + 562176;        // 1622016
    float* part = wsf + 2184192;       // 3538944
    unsigned short* kbf  = (unsigned short*)((char*)d_ws + 22892544);
    unsigned short* vbf  = kbf + 147456;
    unsigned short* kpbf = vbf + 147456;
    unsigned short* vpbf = kpbf + 110592;
    float* out = (float*)d_out;

    k_se<<<192, 256, 0, stream>>>(s, wexp, bexp, ln_g, ln_b, se0);
    k_proj<<<dim3(96, 2), 256, 0, stream>>>(se0, wq, bq, wkv, bkv, wqp, bqp,
                                            wkvp, bkvp, r_rot, r_trans,
                                            qf, kbf, vbf, qpf, kpbf, vpbf, k2w);
    k_attn<<<768, 256, 0, stream>>>(z, mask, head_w, wb, bb, r_rot, r_trans,
                                    qf, qpf, k2w, kbf, vbf, kpbf, vpbf, catb);
    k_gemm<<<dim3(6, 6, 12), 256, 0, stream>>>(catb, wout, part);
    k_red<<<1152, 256, 0, stream>>>(part, bout, out);
}